// Round 1
// baseline (476.964 us; speedup 1.0000x reference)
//
#include <hip/hip_runtime.h>
#include <hip/hip_bf16.h>

#define PI_F 3.14159265358979323846f

// ---------------------------------------------------------------------------
// Kernel 1: per-batch matrix build + analytic 3x3 (affine) inverse.
// mat = trn @ shr @ scl @ rot collapsed analytically:
//   m00 = sx*c + shxy*sy*s ; m01 = -sx*s + shxy*sy*c ; m02 = tx
//   m10 = shyx*sx*c + sy*s ; m11 = -shyx*sx*s + sy*c ; m12 = ty
//   row2 = [0,0,1]
// ---------------------------------------------------------------------------
__global__ void build_mats_kernel(const float* __restrict__ fc2,
                                  float* __restrict__ mat_out,
                                  float* __restrict__ inv_out,
                                  int B) {
    int b = blockIdx.x * blockDim.x + threadIdx.x;
    if (b >= B) return;
    const float* f = fc2 + b * 7;
    float theta = fminf(fmaxf(f[0] * 0.3f, -1.f), 1.f) * PI_F;
    float sx    = fminf(fmaxf(f[1] * 0.3f + 1.f, 0.f), 5.f);
    float sy    = fminf(fmaxf(f[2] * 0.3f + 1.f, 0.f), 5.f);
    float tx    = f[3] * 0.3f;
    float ty    = f[4] * 0.3f;
    float shxy  = fminf(fmaxf(f[5] * 0.3f, -1.f), 1.f) * PI_F;
    float shyx  = fminf(fmaxf(f[6] * 0.3f, -1.f), 1.f) * PI_F;

    float c = cosf(theta), s = sinf(theta);
    float m00 =  sx * c + shxy * sy * s;
    float m01 = -sx * s + shxy * sy * c;
    float m02 = tx;
    float m10 = shyx * sx * c + sy * s;
    float m11 = -shyx * sx * s + sy * c;
    float m12 = ty;

    float* m = mat_out + b * 9;
    m[0] = m00; m[1] = m01; m[2] = m02;
    m[3] = m10; m[4] = m11; m[5] = m12;
    m[6] = 0.f; m[7] = 0.f; m[8] = 1.f;

    // Affine inverse: [[A^-1, -A^-1 t],[0,0,1]]
    float det = m00 * m11 - m01 * m10;
    float id  = 1.f / det;
    float i00 =  m11 * id, i01 = -m01 * id;
    float i10 = -m10 * id, i11 =  m00 * id;
    float i02 = -(i00 * m02 + i01 * m12);
    float i12 = -(i10 * m02 + i11 * m12);

    float* im = inv_out + b * 9;
    im[0] = i00; im[1] = i01; im[2] = i02;
    im[3] = i10; im[4] = i11; im[5] = i12;
    im[6] = 0.f; im[7] = 0.f; im[8] = 1.f;
}

// ---------------------------------------------------------------------------
// Kernel 2: one thread per (b,h,w). Computes grid + inv_grid points, writes
// them as float2, then bilinear-samples 4 channels of src with zero padding.
// b = blockIdx.z is wave-uniform -> matrix loads become scalar loads.
// ---------------------------------------------------------------------------
__global__ __launch_bounds__(256) void affine_main_kernel(
    const float* __restrict__ src,
    const float* __restrict__ mat,
    const float* __restrict__ inv_mat,
    float* __restrict__ transformed,
    float* __restrict__ grid_out,
    float* __restrict__ inv_grid_out)
{
    const int W = 512, H = 512, C = 4;
    int w = blockIdx.x * blockDim.x + threadIdx.x;
    int h = blockIdx.y;
    int b = blockIdx.z;

    float xs = (2.f * (float)w + 1.f) * (1.f / (float)W) - 1.f;
    float ys = (2.f * (float)h + 1.f) * (1.f / (float)H) - 1.f;

    const float* m  = mat + b * 9;
    const float* im = inv_mat + b * 9;
    float gx  = m[0] * xs + m[1] * ys + m[2];
    float gy  = m[3] * xs + m[4] * ys + m[5];
    float igx = im[0] * xs + im[1] * ys + im[2];
    float igy = im[3] * xs + im[4] * ys + im[5];

    size_t pix = ((size_t)b * H + h) * W + w;
    ((float2*)grid_out)[pix]     = make_float2(gx, gy);
    ((float2*)inv_grid_out)[pix] = make_float2(igx, igy);

    // Bilinear sample (align_corners=False convention per reference)
    float ix = ((gx + 1.f) * (float)W - 1.f) * 0.5f;
    float iy = ((gy + 1.f) * (float)H - 1.f) * 0.5f;
    float x0f = floorf(ix), y0f = floorf(iy);
    float wx = ix - x0f, wy = iy - y0f;
    int x0 = (int)x0f, y0 = (int)y0f;
    int x1 = x0 + 1,   y1 = y0 + 1;

    bool vx0 = (x0 >= 0) && (x0 < W);
    bool vx1 = (x1 >= 0) && (x1 < W);
    bool vy0 = (y0 >= 0) && (y0 < H);
    bool vy1 = (y1 >= 0) && (y1 < H);
    int cx0 = min(max(x0, 0), W - 1), cx1 = min(max(x1, 0), W - 1);
    int cy0 = min(max(y0, 0), H - 1), cy1 = min(max(y1, 0), H - 1);

    float w00 = (1.f - wx) * (1.f - wy) * ((vx0 && vy0) ? 1.f : 0.f);
    float w01 = wx * (1.f - wy)         * ((vx1 && vy0) ? 1.f : 0.f);
    float w10 = (1.f - wx) * wy         * ((vx0 && vy1) ? 1.f : 0.f);
    float w11 = wx * wy                 * ((vx1 && vy1) ? 1.f : 0.f);

    const float* sb = src + (size_t)b * C * H * W;
    size_t o00 = (size_t)cy0 * W + cx0;
    size_t o01 = (size_t)cy0 * W + cx1;
    size_t o10 = (size_t)cy1 * W + cx0;
    size_t o11 = (size_t)cy1 * W + cx1;

    #pragma unroll
    for (int c = 0; c < C; ++c) {
        const float* sc = sb + (size_t)c * H * W;
        float v = sc[o00] * w00 + sc[o01] * w01 + sc[o10] * w10 + sc[o11] * w11;
        transformed[(((size_t)b * C + c) * H + h) * W + w] = v;
    }
}

extern "C" void kernel_launch(void* const* d_in, const int* in_sizes, int n_in,
                              void* d_out, int out_size, void* d_ws, size_t ws_size,
                              hipStream_t stream) {
    const float* src = (const float*)d_in[0];   // (32,4,512,512) f32
    const float* fc2 = (const float*)d_in[1];   // (32,7) f32

    const int B = 32, C = 4, H = 512, W = 512;
    float* out = (float*)d_out;

    // Output layout (flat, return order):
    float* transformed  = out;                                   // 33,554,432
    float* mat_out      = out + (size_t)B * C * H * W;           // +288
    float* inv_out      = mat_out + (size_t)B * 9;               // +288
    float* grid_out     = inv_out + (size_t)B * 9;               // +16,777,216
    float* inv_grid_out = grid_out + (size_t)B * H * W * 2;      // +16,777,216

    // Kernel 1: 32 matrices
    build_mats_kernel<<<1, 64, 0, stream>>>(fc2, mat_out, inv_out, B);

    // Kernel 2: per-pixel grids + bilinear sampling
    dim3 grid(W / 256, H, B);
    dim3 block(256);
    affine_main_kernel<<<grid, block, 0, stream>>>(src, mat_out, inv_out,
                                                   transformed, grid_out, inv_grid_out);
}